// Round 1
// baseline (1732.049 us; speedup 1.0000x reference)
//
#include <hip/hip_runtime.h>

// BertClassifier: B=2048, S=256, H=768, INNER=256, NB_CTX=2, NB_EXPERTS=12, NB_LABELS=3
// Derived static context indexes from np.random.default_rng(0).choice(256, size=2):
//   PCG64(SeedSequence(0)) first uint64 raw0 satisfies raw0>>11 = 0.6369616873214543 * 2^53
//   = 5,737,240,835,340,368; Lemire path -> idx = [low32>>24, high32>>24] = [217, 163].
#define B_N 2048
#define S_N 256
#define H_N 768
#define K3 2304
#define INNER_N 256
#define IDX0 217
#define IDX1 163

typedef __attribute__((ext_vector_type(8))) short bf16x8;
typedef __attribute__((ext_vector_type(4))) float f32x4;

__device__ __forceinline__ unsigned short f2bf(float x) {
    union { float f; unsigned int u; } v;
    v.f = x;
    unsigned int u = v.u;
    unsigned int r = (u + 0x7FFFu + ((u >> 16) & 1u)) >> 16;  // RNE
    return (unsigned short)r;
}

// K0: W_base [256][2304] fp32 -> bf16, same layout (this IS the MFMA B-operand layout).
__global__ void k0_convert_w(const float* __restrict__ W, unsigned short* __restrict__ Wb) {
    int i = (blockIdx.x * 256 + threadIdx.x) * 4;  // 589824 = 576*256*4 exact
    float4 v = *(const float4*)(W + i);
    ushort4 o;
    o.x = f2bf(v.x); o.y = f2bf(v.y); o.z = f2bf(v.z); o.w = f2bf(v.w);
    *(ushort4*)(Wb + i) = o;
}

// K1: build feat bf16 [2048][2304] = [span-mean | emb[:,217,:] | emb[:,163,:]]
__global__ void k1_feat(const float* __restrict__ emb, const int* __restrict__ pos,
                        unsigned short* __restrict__ feat) {
    int b = blockIdx.x;
    int t = threadIdx.x;  // 256 threads
    const float* eb = emb + (size_t)b * (S_N * H_N);
    int start = pos[2 * b], stop = pos[2 * b + 1];
    float inv = 1.0f / (float)(stop - start);
    unsigned short* fb = feat + (size_t)b * K3;
    for (int h = t; h < H_N; h += 256) {
        float s = 0.0f;
        for (int p = start; p < stop; ++p) s += eb[p * H_N + h];
        fb[h]             = f2bf(s * inv);
        fb[H_N + h]       = f2bf(eb[IDX0 * H_N + h]);
        fb[2 * H_N + h]   = f2bf(eb[IDX1 * H_N + h]);
    }
}

// K2: hidden[2048][256] = relu(feat @ W_base^T + b_base), bf16 MFMA 16x16x32.
// grid (128, 2), block 256 = 4 waves. Wave w: m-tile = blockIdx.x, n-cols
// [blockIdx.y*128 + w*32, +32) as two 16x16 tiles. No LDS: fragments loaded
// directly from global as 16B short8 (A[m=lane&15][k=quad*8+j]; B from [n][k]
// rows gives D = A . W^T). C/D: col=lane&15, row=quad*4+reg (verified layout).
__global__ __launch_bounds__(256) void k2_gemm(const unsigned short* __restrict__ feat,
                                               const unsigned short* __restrict__ Wb,
                                               const float* __restrict__ bb,
                                               float* __restrict__ hidden) {
    int tid = threadIdx.x;
    int w = tid >> 6;
    int L = tid & 63;
    int lm = L & 15;
    int q = L >> 4;
    int m0 = blockIdx.x * 16;
    int n0 = blockIdx.y * 128 + w * 32;
    const short* fa = (const short*)feat + (size_t)(m0 + lm) * K3 + q * 8;
    const short* w0 = (const short*)Wb + (size_t)(n0 + lm) * K3 + q * 8;
    const short* w1 = w0 + 16 * K3;
    f32x4 acc0 = {0.f, 0.f, 0.f, 0.f};
    f32x4 acc1 = {0.f, 0.f, 0.f, 0.f};
#pragma unroll 8
    for (int k = 0; k < K3; k += 32) {
        bf16x8 a  = *(const bf16x8*)(fa + k);
        bf16x8 b0 = *(const bf16x8*)(w0 + k);
        bf16x8 b1 = *(const bf16x8*)(w1 + k);
        acc0 = __builtin_amdgcn_mfma_f32_16x16x32_bf16(a, b0, acc0, 0, 0, 0);
        acc1 = __builtin_amdgcn_mfma_f32_16x16x32_bf16(a, b1, acc1, 0, 0, 0);
    }
    int nc = n0 + lm;
    float bias0 = bb[nc];
    float bias1 = bb[nc + 16];
#pragma unroll
    for (int r = 0; r < 4; ++r) {
        int m = m0 + q * 4 + r;
        float v0 = acc0[r] + bias0;
        float v1 = acc1[r] + bias1;
        hidden[(size_t)m * INNER_N + nc]      = v0 > 0.f ? v0 : 0.f;
        hidden[(size_t)m * INNER_N + nc + 16] = v1 > 0.f ? v1 : 0.f;
    }
}

// K3: out[b][n] = hidden[b,:] . W_experts[cat[b]][n,:] + b_experts[cat[b]][n]
// One wave per sample (4 waves/block), float4 loads + shuffle reduction.
__global__ void k3_experts(const float* __restrict__ hidden, const int* __restrict__ cat,
                           const float* __restrict__ We, const float* __restrict__ be,
                           float* __restrict__ out) {
    int b = blockIdx.x * 4 + (threadIdx.x >> 6);
    int L = threadIdx.x & 63;
    float4 h = *(const float4*)(hidden + (size_t)b * INNER_N + L * 4);
    int c = cat[b];
    const float* W = We + c * (3 * INNER_N);
    float4 wv0 = *(const float4*)(W + 0 * INNER_N + L * 4);
    float4 wv1 = *(const float4*)(W + 1 * INNER_N + L * 4);
    float4 wv2 = *(const float4*)(W + 2 * INNER_N + L * 4);
    float r0 = h.x * wv0.x + h.y * wv0.y + h.z * wv0.z + h.w * wv0.w;
    float r1 = h.x * wv1.x + h.y * wv1.y + h.z * wv1.z + h.w * wv1.w;
    float r2 = h.x * wv2.x + h.y * wv2.y + h.z * wv2.z + h.w * wv2.w;
#pragma unroll
    for (int off = 32; off > 0; off >>= 1) {
        r0 += __shfl_down(r0, off);
        r1 += __shfl_down(r1, off);
        r2 += __shfl_down(r2, off);
    }
    if (L == 0) {
        out[b * 3 + 0] = r0 + be[c * 3 + 0];
        out[b * 3 + 1] = r1 + be[c * 3 + 1];
        out[b * 3 + 2] = r2 + be[c * 3 + 2];
    }
}

extern "C" void kernel_launch(void* const* d_in, const int* in_sizes, int n_in,
                              void* d_out, int out_size, void* d_ws, size_t ws_size,
                              hipStream_t stream) {
    const float* emb   = (const float*)d_in[0];
    const int*   pos   = (const int*)d_in[1];
    const int*   cat   = (const int*)d_in[2];
    const float* Wbase = (const float*)d_in[3];
    const float* bbase = (const float*)d_in[4];
    const float* Wexp  = (const float*)d_in[5];
    const float* bexp  = (const float*)d_in[6];
    float* out = (float*)d_out;

    char* ws = (char*)d_ws;
    // ws layout: W_bf16 (1,179,648 B) | feat bf16 (9,437,184 B) | hidden fp32 (2,097,152 B)
    unsigned short* Wb   = (unsigned short*)ws;
    unsigned short* feat = (unsigned short*)(ws + 1179648);
    float*          hid  = (float*)(ws + 1179648 + 9437184);

    hipLaunchKernelGGL(k0_convert_w, dim3(576), dim3(256), 0, stream, Wbase, Wb);
    hipLaunchKernelGGL(k1_feat, dim3(2048), dim3(256), 0, stream, emb, pos, feat);
    hipLaunchKernelGGL(k2_gemm, dim3(128, 2), dim3(256), 0, stream, feat, Wb, bbase, hid);
    hipLaunchKernelGGL(k3_experts, dim3(512), dim3(256), 0, stream, hid, cat, Wexp, bexp, out);
}

// Round 2
// 1708.053 us; speedup vs baseline: 1.0140x; 1.0140x over previous
//
#include <hip/hip_runtime.h>

// BertClassifier: B=2048, S=256, H=768, INNER=256, NB_CTX=2, NB_EXPERTS=12, NB_LABELS=3
// Static context indexes derived from np.random.default_rng(0).choice(256, size=2):
//   PCG64(SeedSequence(0)) Lemire path -> [217, 163]. Validated in round 1 (absmax 3.9e-3).
#define B_N 2048
#define S_N 256
#define H_N 768
#define K3 2304
#define INNER_N 256
#define IDX0 217
#define IDX1 163
#define KITERS 72        // 2304 / 32
#define ARS 2312         // A-tile LDS row stride in shorts (2304 + 8 pad -> 16B-aligned rows, +4-bank rotation)
#define HRS 260          // hidden LDS row stride in floats (16B-aligned rows)

typedef __attribute__((ext_vector_type(8))) short bf16x8;
typedef __attribute__((ext_vector_type(4))) float f32x4;

__device__ __forceinline__ unsigned short f2bf(float x) {
    union { float f; unsigned int u; } v;
    v.f = x;
    unsigned int u = v.u;
    return (unsigned short)((u + 0x7FFFu + ((u >> 16) & 1u)) >> 16);  // RNE
}

// k0: pack W_base fp32 [256][2304] into bf16 MFMA B-fragment stream:
// Wpk[tile][ki][lane][j8]  with n = tile*16 + (lane&15), k = ki*32 + (lane>>4)*8 + j.
// GEMM waves then read one contiguous 1KB line per (tile, k-iter) -> perfect coalescing.
__global__ void k0_pack_w(const float* __restrict__ W, unsigned short* __restrict__ Wpk) {
    int g = blockIdx.x * 256 + threadIdx.x;          // 73728 = 16*72*64 groups of 8
    int L = g & 63;
    int gi = g >> 6;                                  // tile*72 + ki
    int ki = gi % KITERS;
    int tile = gi / KITERS;
    int n = tile * 16 + (L & 15);
    int k = ki * 32 + (L >> 4) * 8;
    const float* src = W + (size_t)n * K3 + k;
    float4 v0 = *(const float4*)(src);
    float4 v1 = *(const float4*)(src + 4);
    ushort4 o0, o1;
    o0.x = f2bf(v0.x); o0.y = f2bf(v0.y); o0.z = f2bf(v0.z); o0.w = f2bf(v0.w);
    o1.x = f2bf(v1.x); o1.y = f2bf(v1.y); o1.z = f2bf(v1.z); o1.w = f2bf(v1.w);
    unsigned short* dst = Wpk + (size_t)g * 8;
    *(ushort4*)(dst)     = o0;
    *(ushort4*)(dst + 4) = o1;
}

// Fused: feat-build (LDS) -> GEMM+bias+ReLU (LDS) -> expert heads -> out.
// 256 blocks x 512 threads; block owns samples [blockIdx.x*8, +8).
__global__ __launch_bounds__(512) void k_fused(
        const float* __restrict__ emb, const int* __restrict__ pos,
        const int* __restrict__ cat, const unsigned short* __restrict__ Wpk,
        const float* __restrict__ bb, const float* __restrict__ We,
        const float* __restrict__ be, float* __restrict__ out) {
    __shared__ unsigned short A[9 * ARS];   // 41,616 B: 8 sample rows + zero row 8
    __shared__ float Hd[8 * HRS];           // 8,320 B
    int tid = threadIdx.x;
    int b0 = blockIdx.x * 8;
    int w = tid >> 6;        // wave 0..7 (== sample index in stages 1 & 3)
    int L = tid & 63;

    // zero the pad row (rows 8..15 of the MFMA m-dim read this, broadcast)
    for (int i = tid; i < ARS; i += 512) A[8 * ARS + i] = 0;

    // ---- stage 1: feat tile [8][2304] bf16 = [span-mean | emb[:,217,:] | emb[:,163,:]]
    {
        int b = b0 + w;
        const float* eb = emb + (size_t)b * (S_N * H_N);
        int start = pos[2 * b], stop = pos[2 * b + 1];
        float inv = 1.0f / (float)(stop - start);
        unsigned short* arow = &A[w * ARS];
#pragma unroll
        for (int p = 0; p < 3; ++p) {
            int c4 = (L + p * 64) * 4;                 // float col 0..764
            float4 s; s.x = s.y = s.z = s.w = 0.f;
            for (int r = start; r < stop; ++r) {
                float4 v = *(const float4*)(eb + r * H_N + c4);
                s.x += v.x; s.y += v.y; s.z += v.z; s.w += v.w;
            }
            float4 c0 = *(const float4*)(eb + IDX0 * H_N + c4);
            float4 c1 = *(const float4*)(eb + IDX1 * H_N + c4);
            ushort4 om, o0, o1;
            om.x = f2bf(s.x * inv); om.y = f2bf(s.y * inv);
            om.z = f2bf(s.z * inv); om.w = f2bf(s.w * inv);
            o0.x = f2bf(c0.x); o0.y = f2bf(c0.y); o0.z = f2bf(c0.z); o0.w = f2bf(c0.w);
            o1.x = f2bf(c1.x); o1.y = f2bf(c1.y); o1.z = f2bf(c1.z); o1.w = f2bf(c1.w);
            *(ushort4*)(arow + c4)            = om;
            *(ushort4*)(arow + H_N + c4)      = o0;
            *(ushort4*)(arow + 2 * H_N + c4)  = o1;
        }
    }
    __syncthreads();

    // ---- stage 2: hidden[8][256] = relu(feat @ W_base^T + b); wave w -> n-cols [w*32, +32)
    {
        int lm = L & 15, q = L >> 4;
        int arow = (lm < 8) ? lm : 8;                  // rows 8..15 -> zero row (LDS broadcast)
        const unsigned short* a_ptr = &A[arow * ARS + q * 8];
        const unsigned short* bp0 = Wpk + ((size_t)(2 * w) * KITERS * 64 + L) * 8;
        const unsigned short* bp1 = Wpk + ((size_t)(2 * w + 1) * KITERS * 64 + L) * 8;
        f32x4 acc0 = {0.f, 0.f, 0.f, 0.f};
        f32x4 acc1 = {0.f, 0.f, 0.f, 0.f};
#pragma unroll 4
        for (int ki = 0; ki < KITERS; ++ki) {
            bf16x8 a  = *(const bf16x8*)(a_ptr + ki * 32);
            bf16x8 v0 = *(const bf16x8*)(bp0 + ki * 512);
            bf16x8 v1 = *(const bf16x8*)(bp1 + ki * 512);
            acc0 = __builtin_amdgcn_mfma_f32_16x16x32_bf16(a, v0, acc0, 0, 0, 0);
            acc1 = __builtin_amdgcn_mfma_f32_16x16x32_bf16(a, v1, acc1, 0, 0, 0);
        }
        if (q < 2) {                                   // valid m rows are 0..7
            int nc0 = w * 32 + lm, nc1 = w * 32 + 16 + lm;
            float bias0 = bb[nc0], bias1 = bb[nc1];
#pragma unroll
            for (int r = 0; r < 4; ++r) {
                int m = q * 4 + r;                     // C/D: row = (lane>>4)*4 + reg
                float v0 = acc0[r] + bias0;
                float v1 = acc1[r] + bias1;
                Hd[m * HRS + nc0] = v0 > 0.f ? v0 : 0.f;
                Hd[m * HRS + nc1] = v1 > 0.f ? v1 : 0.f;
            }
        }
    }
    __syncthreads();

    // ---- stage 3: out[b][n] = hidden[b,:] . We[cat[b]][n,:] + be[cat[b]][n]; wave w -> sample w
    {
        int b = b0 + w;
        int c = cat[b];
        float4 h = *(const float4*)(&Hd[w * HRS + 4 * L]);
        const float* Wr = We + (size_t)c * (3 * INNER_N);
        float4 e0 = *(const float4*)(Wr + 0 * INNER_N + 4 * L);
        float4 e1 = *(const float4*)(Wr + 1 * INNER_N + 4 * L);
        float4 e2 = *(const float4*)(Wr + 2 * INNER_N + 4 * L);
        float r0 = h.x * e0.x + h.y * e0.y + h.z * e0.z + h.w * e0.w;
        float r1 = h.x * e1.x + h.y * e1.y + h.z * e1.z + h.w * e1.w;
        float r2 = h.x * e2.x + h.y * e2.y + h.z * e2.z + h.w * e2.w;
#pragma unroll
        for (int off = 32; off > 0; off >>= 1) {
            r0 += __shfl_down(r0, off);
            r1 += __shfl_down(r1, off);
            r2 += __shfl_down(r2, off);
        }
        if (L == 0) {
            out[b * 3 + 0] = r0 + be[c * 3 + 0];
            out[b * 3 + 1] = r1 + be[c * 3 + 1];
            out[b * 3 + 2] = r2 + be[c * 3 + 2];
        }
    }
}

extern "C" void kernel_launch(void* const* d_in, const int* in_sizes, int n_in,
                              void* d_out, int out_size, void* d_ws, size_t ws_size,
                              hipStream_t stream) {
    const float* emb   = (const float*)d_in[0];
    const int*   pos   = (const int*)d_in[1];
    const int*   cat   = (const int*)d_in[2];
    const float* Wbase = (const float*)d_in[3];
    const float* bbase = (const float*)d_in[4];
    const float* Wexp  = (const float*)d_in[5];
    const float* bexp  = (const float*)d_in[6];
    float* out = (float*)d_out;

    unsigned short* Wpk = (unsigned short*)d_ws;   // 16*72*64*8 shorts = 1,179,648 B

    hipLaunchKernelGGL(k0_pack_w, dim3(288), dim3(256), 0, stream, Wbase, Wpk);
    hipLaunchKernelGGL(k_fused, dim3(256), dim3(512), 0, stream,
                       emb, pos, cat, Wpk, bbase, Wexp, bexp, out);
}